// Round 1
// baseline (1427.890 us; speedup 1.0000x reference)
//
#include <hip/hip_runtime.h>
#include <math.h>

// Problem constants (fixed by setup_inputs)
constexpr int B_   = 2;
constexpr int C_   = 64;
constexpr int H_   = 128;
constexpr int W_   = 128;
constexpr int HW_  = H_ * W_;
constexpr int DG_  = 16;   // deformable groups
constexpr int KK_  = 9;    // 3x3 taps
constexpr int CG_  = 4;    // channels per group = C/DG
constexpr int OFFC_ = 3 * KK_ * DG_;  // 432

// ---------------------------------------------------------------------------
// Direct 3x3 conv, pad=1, stride=1. Each thread: one pixel, 16 output chans.
// Weight addresses are wave-uniform -> scalar loads; 1 vector load / 16 FMA.
// ---------------------------------------------------------------------------
template <int CIN, int COUT>
__global__ __launch_bounds__(256) void conv3x3_leaky_k(
    const float* __restrict__ in, const float* __restrict__ wgt,
    const float* __restrict__ bias, float* __restrict__ out)
{
    const int xp = blockIdx.x * 16 + threadIdx.x;
    const int yp = blockIdx.y * 16 + threadIdx.y;
    const int z  = blockIdx.z;
    constexpr int NCHUNK = COUT / 16;
    const int b   = z / NCHUNK;
    const int ocb = (z % NCHUNK) * 16;

    float acc[16];
#pragma unroll
    for (int o = 0; o < 16; ++o) acc[o] = bias[ocb + o];

    const float* inb = in + (size_t)b * CIN * HW_;
    for (int ic = 0; ic < CIN; ++ic) {
        const float* inc = inb + (size_t)ic * HW_;
        const float* wic = wgt + ((size_t)ocb * CIN + ic) * 9;
#pragma unroll
        for (int ky = 0; ky < 3; ++ky) {
            const int yy = yp + ky - 1;
            const bool vy = ((unsigned)yy < (unsigned)H_);
#pragma unroll
            for (int kx = 0; kx < 3; ++kx) {
                const int xx = xp + kx - 1;
                float v = 0.f;
                if (vy && ((unsigned)xx < (unsigned)W_)) v = inc[yy * W_ + xx];
                const float* wp = wic + ky * 3 + kx;
#pragma unroll
                for (int o = 0; o < 16; ++o)
                    acc[o] = fmaf(v, wp[(size_t)o * CIN * 9], acc[o]);
            }
        }
    }

    const int pix = yp * W_ + xp;
#pragma unroll
    for (int o = 0; o < 16; ++o) {
        float r = acc[o];
        r = (r >= 0.f) ? r : 0.1f * r;
        out[((size_t)(b * COUT + ocb + o)) * HW_ + pix] = r;
    }
}

// ---------------------------------------------------------------------------
// Conv3 (64 -> 432) with fused offset/mask epilogue.
// Output layout: omap[b][g*9+k][slot][H][W], slot 0=off_y 1=off_x 2=mask.
// off = 10*tanh(o[:288]) + flow_yx tiled; mask = sigmoid(o[288:432]).
// flow_yx = flow[:, ::-1]  -> y-offset gets flow ch1, x-offset gets flow ch0.
// ---------------------------------------------------------------------------
__global__ __launch_bounds__(256) void conv3_off_k(
    const float* __restrict__ in, const float* __restrict__ wgt,
    const float* __restrict__ bias, const float* __restrict__ flow,
    float* __restrict__ omap)
{
    const int xp = blockIdx.x * 16 + threadIdx.x;
    const int yp = blockIdx.y * 16 + threadIdx.y;
    const int z  = blockIdx.z;
    constexpr int CIN = 64;
    constexpr int NCHUNK = OFFC_ / 16;   // 27
    const int b   = z / NCHUNK;
    const int ocb = (z % NCHUNK) * 16;

    float acc[16];
#pragma unroll
    for (int o = 0; o < 16; ++o) acc[o] = bias[ocb + o];

    const float* inb = in + (size_t)b * CIN * HW_;
    for (int ic = 0; ic < CIN; ++ic) {
        const float* inc = inb + (size_t)ic * HW_;
        const float* wic = wgt + ((size_t)ocb * CIN + ic) * 9;
#pragma unroll
        for (int ky = 0; ky < 3; ++ky) {
            const int yy = yp + ky - 1;
            const bool vy = ((unsigned)yy < (unsigned)H_);
#pragma unroll
            for (int kx = 0; kx < 3; ++kx) {
                const int xx = xp + kx - 1;
                float v = 0.f;
                if (vy && ((unsigned)xx < (unsigned)W_)) v = inc[yy * W_ + xx];
                const float* wp = wic + ky * 3 + kx;
#pragma unroll
                for (int o = 0; o < 16; ++o)
                    acc[o] = fmaf(v, wp[(size_t)o * CIN * 9], acc[o]);
            }
        }
    }

    const int pix = yp * W_ + xp;
#pragma unroll
    for (int o = 0; o < 16; ++o) {
        const int oc = ocb + o;
        float val = acc[o];
        int g, k, slot;
        if (oc < 2 * DG_ * KK_) {          // offset channels (0..287)
            g = oc / 18;
            const int rem = oc - g * 18;
            k = rem >> 1;
            slot = rem & 1;                 // 0 = y, 1 = x
            const float fl = flow[(size_t)(b * 2 + (1 - slot)) * HW_ + pix];
            val = 10.f * tanhf(val) + fl;
        } else {                            // mask channels (288..431)
            const int c = oc - 2 * DG_ * KK_;
            g = c / 9;
            k = c - g * 9;
            slot = 2;
            val = 1.f / (1.f + expf(-val));
        }
        omap[((size_t)((b * DG_ * KK_ + g * KK_ + k) * 3 + slot)) * HW_ + pix] = val;
    }
}

// ---------------------------------------------------------------------------
// Deformable gather + einsum. Thread = (pixel, 16-out-channel chunk).
// wk[o][g][c][k] = weight[o*576 + (g*4+c)*9 + k]
// ---------------------------------------------------------------------------
__global__ __launch_bounds__(256) void deform_k(
    const float* __restrict__ x, const float* __restrict__ omap,
    const float* __restrict__ wk, float* __restrict__ out)
{
    const int xp = blockIdx.x * 16 + threadIdx.x;
    const int yp = blockIdx.y * 16 + threadIdx.y;
    const int z  = blockIdx.z;
    const int b   = z >> 2;
    const int ocb = (z & 3) * 16;

    float acc[16];
#pragma unroll
    for (int o = 0; o < 16; ++o) acc[o] = 0.f;

    const float* xb = x + (size_t)b * C_ * HW_;
    const int pix = yp * W_ + xp;

    for (int g = 0; g < DG_; ++g) {
#pragma unroll
        for (int k = 0; k < KK_; ++k) {
            const size_t obase = ((size_t)((b * DG_ * KK_ + g * KK_ + k) * 3)) * HW_ + pix;
            const float oy = omap[obase];
            const float ox = omap[obase + HW_];
            const float m  = omap[obase + 2 * HW_];

            const float py = (float)(yp + (k / 3) - 1) + oy;
            const float px = (float)(xp + (k % 3) - 1) + ox;
            const float y0f = floorf(py);
            const float x0f = floorf(px);
            const float wy = py - y0f;
            const float wx = px - x0f;
            const int y0 = (int)y0f, x0 = (int)x0f;
            const int y1 = y0 + 1,  x1 = x0 + 1;
            const bool vy0 = ((unsigned)y0 < (unsigned)H_);
            const bool vy1 = ((unsigned)y1 < (unsigned)H_);
            const bool vx0 = ((unsigned)x0 < (unsigned)W_);
            const bool vx1 = ((unsigned)x1 < (unsigned)W_);
            const float w00 = (1.f - wy) * (1.f - wx);
            const float w01 = (1.f - wy) * wx;
            const float w10 = wy * (1.f - wx);
            const float w11 = wy * wx;

#pragma unroll
            for (int c = 0; c < CG_; ++c) {
                const float* img = xb + (size_t)(g * CG_ + c) * HW_;
                float v = 0.f;
                if (vy0 && vx0) v = fmaf(w00, img[y0 * W_ + x0], v);
                if (vy0 && vx1) v = fmaf(w01, img[y0 * W_ + x1], v);
                if (vy1 && vx0) v = fmaf(w10, img[y1 * W_ + x0], v);
                if (vy1 && vx1) v = fmaf(w11, img[y1 * W_ + x1], v);
                const float s = v * m;
                const float* wp = wk + (size_t)ocb * (C_ * 9) + (size_t)(g * CG_ + c) * 9 + k;
#pragma unroll
                for (int o = 0; o < 16; ++o)
                    acc[o] = fmaf(s, wp[(size_t)o * C_ * 9], acc[o]);
            }
        }
    }

#pragma unroll
    for (int o = 0; o < 16; ++o)
        out[((size_t)(b * C_ + ocb + o)) * HW_ + pix] = acc[o];
}

// ---------------------------------------------------------------------------
extern "C" void kernel_launch(void* const* d_in, const int* in_sizes, int n_in,
                              void* d_out, int out_size, void* d_ws, size_t ws_size,
                              hipStream_t stream)
{
    const float* x    = (const float*)d_in[0];
    const float* ef   = (const float*)d_in[1];
    const float* flow = (const float*)d_in[2];
    const float* w1   = (const float*)d_in[3];
    const float* b1   = (const float*)d_in[4];
    const float* w2   = (const float*)d_in[5];
    const float* b2   = (const float*)d_in[6];
    const float* w3   = (const float*)d_in[7];
    const float* b3   = (const float*)d_in[8];
    const float* wk   = (const float*)d_in[9];
    float* out = (float*)d_out;

    // Workspace layout (floats):
    //   h1: B*64*HW      = 2,097,152
    //   h2: B*64*HW      = 2,097,152
    //   om: B*432*HW     = 14,155,776   (total 73.4 MB)
    float* h1 = (float*)d_ws;
    float* h2 = h1 + (size_t)B_ * C_ * HW_;
    float* om = h2 + (size_t)B_ * C_ * HW_;

    dim3 blk(16, 16, 1);
    conv3x3_leaky_k<2 * C_, C_><<<dim3(W_ / 16, H_ / 16, B_ * (C_ / 16)), blk, 0, stream>>>(ef, w1, b1, h1);
    conv3x3_leaky_k<C_, C_><<<dim3(W_ / 16, H_ / 16, B_ * (C_ / 16)), blk, 0, stream>>>(h1, w2, b2, h2);
    conv3_off_k<<<dim3(W_ / 16, H_ / 16, B_ * (OFFC_ / 16)), blk, 0, stream>>>(h2, w3, b3, flow, om);
    deform_k<<<dim3(W_ / 16, H_ / 16, B_ * (C_ / 16)), blk, 0, stream>>>(x, om, wk, out);
}

// Round 2
// 871.658 us; speedup vs baseline: 1.6381x; 1.6381x over previous
//
#include <hip/hip_runtime.h>
#include <math.h>

// Problem constants (fixed by setup_inputs)
constexpr int B_   = 2;
constexpr int C_   = 64;
constexpr int H_   = 128;
constexpr int W_   = 128;
constexpr int HW_  = H_ * W_;
constexpr int DG_  = 16;   // deformable groups
constexpr int KK_  = 9;    // 3x3 taps
constexpr int CG_  = 4;    // channels per group = C/DG
constexpr int OFFC_ = 3 * KK_ * DG_;  // 432

// ---------------------------------------------------------------------------
// Weight transpose: in[OC][IC9] -> out[IC9][OC]  (OC contiguous so the conv
// kernels can fetch 16 consecutive output-channel weights with one
// s_load_dwordx16 instead of 16 strided s_load_dword).
// ---------------------------------------------------------------------------
template <int OC, int IC9>
__global__ __launch_bounds__(256) void transpose_w_k(
    const float* __restrict__ in, float* __restrict__ out)
{
    const int j = blockIdx.x * 256 + threadIdx.x;
    if (j >= OC * IC9) return;
    const int row = j / OC;   // ic*9 + tap
    const int col = j - row * OC;
    out[j] = in[(size_t)col * IC9 + row];
}

// ---------------------------------------------------------------------------
// Direct 3x3 conv, pad=1. Thread: 1 pixel-column of PX pixels x 16 out chans.
// Weights pre-transposed to [ic*9+t][COUT] -> wave-uniform contiguous loads.
// ---------------------------------------------------------------------------
template <int CIN, int COUT, int PX>
__global__ __launch_bounds__(256) void conv3x3_leaky_k(
    const float* __restrict__ in, const float* __restrict__ wt,
    const float* __restrict__ bias, float* __restrict__ out)
{
    const int xp = blockIdx.x * 16 + threadIdx.x;
    const int yb = (blockIdx.y * 16 + threadIdx.y) * PX;
    const int z  = blockIdx.z;
    constexpr int NCHUNK = COUT / 16;
    const int b   = z / NCHUNK;
    const int ocb = (z % NCHUNK) * 16;

    float acc[PX][16];
#pragma unroll
    for (int p = 0; p < PX; ++p)
#pragma unroll
        for (int o = 0; o < 16; ++o) acc[p][o] = bias[ocb + o];

    const bool vxm = (xp - 1 >= 0);
    const bool vxp = (xp + 1 < W_);
    bool vr[PX + 2];
#pragma unroll
    for (int r = 0; r < PX + 2; ++r)
        vr[r] = ((unsigned)(yb + r - 1) < (unsigned)H_);

    const float* inb = in + (size_t)b * CIN * HW_;
    for (int ic = 0; ic < CIN; ++ic) {
        const float* inc = inb + (size_t)ic * HW_;
        // register-cache the (PX+2) x 3 input patch
        float rv[PX + 2][3];
#pragma unroll
        for (int r = 0; r < PX + 2; ++r) {
            const int yy = yb + r - 1;
            const float* rowp = inc + yy * W_ + xp;
            rv[r][0] = (vr[r] && vxm) ? rowp[-1] : 0.f;
            rv[r][1] = vr[r] ? rowp[0] : 0.f;
            rv[r][2] = (vr[r] && vxp) ? rowp[1] : 0.f;
        }
        const float* wrow = wt + (size_t)(ic * 9) * COUT + ocb;
#pragma unroll
        for (int t = 0; t < 9; ++t) {
            float wv[16];
#pragma unroll
            for (int o = 0; o < 16; ++o) wv[o] = wrow[(size_t)t * COUT + o];
#pragma unroll
            for (int p = 0; p < PX; ++p) {
                const float v = rv[p + t / 3][t % 3];
#pragma unroll
                for (int o = 0; o < 16; ++o)
                    acc[p][o] = fmaf(v, wv[o], acc[p][o]);
            }
        }
    }

#pragma unroll
    for (int p = 0; p < PX; ++p) {
        const int pix = (yb + p) * W_ + xp;
#pragma unroll
        for (int o = 0; o < 16; ++o) {
            float r = acc[p][o];
            r = (r >= 0.f) ? r : 0.1f * r;
            out[((size_t)(b * COUT + ocb + o)) * HW_ + pix] = r;
        }
    }
}

// ---------------------------------------------------------------------------
// Conv3 (64 -> 432) with fused offset/mask epilogue, 2 pixels/thread.
// omap[b][g*9+k][slot][H][W], slot 0=off_y 1=off_x 2=mask.
// ---------------------------------------------------------------------------
template <int PX>
__global__ __launch_bounds__(256) void conv3_off_k(
    const float* __restrict__ in, const float* __restrict__ wt,
    const float* __restrict__ bias, const float* __restrict__ flow,
    float* __restrict__ omap)
{
    const int xp = blockIdx.x * 16 + threadIdx.x;
    const int yb = (blockIdx.y * 16 + threadIdx.y) * PX;
    const int z  = blockIdx.z;
    constexpr int CIN = 64;
    constexpr int COUT = OFFC_;
    constexpr int NCHUNK = COUT / 16;   // 27
    const int b   = z / NCHUNK;
    const int ocb = (z % NCHUNK) * 16;

    float acc[PX][16];
#pragma unroll
    for (int p = 0; p < PX; ++p)
#pragma unroll
        for (int o = 0; o < 16; ++o) acc[p][o] = bias[ocb + o];

    const bool vxm = (xp - 1 >= 0);
    const bool vxp = (xp + 1 < W_);
    bool vr[PX + 2];
#pragma unroll
    for (int r = 0; r < PX + 2; ++r)
        vr[r] = ((unsigned)(yb + r - 1) < (unsigned)H_);

    const float* inb = in + (size_t)b * CIN * HW_;
    for (int ic = 0; ic < CIN; ++ic) {
        const float* inc = inb + (size_t)ic * HW_;
        float rv[PX + 2][3];
#pragma unroll
        for (int r = 0; r < PX + 2; ++r) {
            const int yy = yb + r - 1;
            const float* rowp = inc + yy * W_ + xp;
            rv[r][0] = (vr[r] && vxm) ? rowp[-1] : 0.f;
            rv[r][1] = vr[r] ? rowp[0] : 0.f;
            rv[r][2] = (vr[r] && vxp) ? rowp[1] : 0.f;
        }
        const float* wrow = wt + (size_t)(ic * 9) * COUT + ocb;
#pragma unroll
        for (int t = 0; t < 9; ++t) {
            float wv[16];
#pragma unroll
            for (int o = 0; o < 16; ++o) wv[o] = wrow[(size_t)t * COUT + o];
#pragma unroll
            for (int p = 0; p < PX; ++p) {
                const float v = rv[p + t / 3][t % 3];
#pragma unroll
                for (int o = 0; o < 16; ++o)
                    acc[p][o] = fmaf(v, wv[o], acc[p][o]);
            }
        }
    }

#pragma unroll
    for (int p = 0; p < PX; ++p) {
        const int pix = (yb + p) * W_ + xp;
#pragma unroll
        for (int o = 0; o < 16; ++o) {
            const int oc = ocb + o;
            float val = acc[p][o];
            int g, k, slot;
            if (oc < 2 * DG_ * KK_) {          // offset channels (0..287)
                g = oc / 18;
                const int rem = oc - g * 18;
                k = rem >> 1;
                slot = rem & 1;                 // 0 = y, 1 = x
                const float fl = flow[(size_t)(b * 2 + (1 - slot)) * HW_ + pix];
                val = 10.f * tanhf(val) + fl;
            } else {                            // mask channels (288..431)
                const int c = oc - 2 * DG_ * KK_;
                g = c / 9;
                k = c - g * 9;
                slot = 2;
                val = 1.f / (1.f + expf(-val));
            }
            omap[((size_t)((b * DG_ * KK_ + g * KK_ + k) * 3 + slot)) * HW_ + pix] = val;
        }
    }
}

// ---------------------------------------------------------------------------
// Deformable gather + einsum. Thread = (pixel, 16-out-channel chunk).
// Weights pre-transposed: wkT[(g*4+c)*9 + k][64 oc] -> one x16 scalar load.
// ---------------------------------------------------------------------------
__global__ __launch_bounds__(256) void deform_k(
    const float* __restrict__ x, const float* __restrict__ omap,
    const float* __restrict__ wkT, float* __restrict__ out)
{
    const int xp = blockIdx.x * 16 + threadIdx.x;
    const int yp = blockIdx.y * 16 + threadIdx.y;
    const int z  = blockIdx.z;
    const int b   = z >> 2;
    const int ocb = (z & 3) * 16;

    float acc[16];
#pragma unroll
    for (int o = 0; o < 16; ++o) acc[o] = 0.f;

    const float* xb = x + (size_t)b * C_ * HW_;
    const int pix = yp * W_ + xp;

    for (int g = 0; g < DG_; ++g) {
#pragma unroll
        for (int k = 0; k < KK_; ++k) {
            const size_t obase = ((size_t)((b * DG_ * KK_ + g * KK_ + k) * 3)) * HW_ + pix;
            const float oy = omap[obase];
            const float ox = omap[obase + HW_];
            const float m  = omap[obase + 2 * HW_];

            const float py = (float)(yp + (k / 3) - 1) + oy;
            const float px = (float)(xp + (k % 3) - 1) + ox;
            const float y0f = floorf(py);
            const float x0f = floorf(px);
            const float wy = py - y0f;
            const float wx = px - x0f;
            const int y0 = (int)y0f, x0 = (int)x0f;
            const int y1 = y0 + 1,  x1 = x0 + 1;
            const bool vy0 = ((unsigned)y0 < (unsigned)H_);
            const bool vy1 = ((unsigned)y1 < (unsigned)H_);
            const bool vx0 = ((unsigned)x0 < (unsigned)W_);
            const bool vx1 = ((unsigned)x1 < (unsigned)W_);
            const float w00 = (1.f - wy) * (1.f - wx);
            const float w01 = (1.f - wy) * wx;
            const float w10 = wy * (1.f - wx);
            const float w11 = wy * wx;

#pragma unroll
            for (int c = 0; c < CG_; ++c) {
                const float* img = xb + (size_t)(g * CG_ + c) * HW_;
                float v = 0.f;
                if (vy0 && vx0) v = fmaf(w00, img[y0 * W_ + x0], v);
                if (vy0 && vx1) v = fmaf(w01, img[y0 * W_ + x1], v);
                if (vy1 && vx0) v = fmaf(w10, img[y1 * W_ + x0], v);
                if (vy1 && vx1) v = fmaf(w11, img[y1 * W_ + x1], v);
                const float s = v * m;
                const float* wp = wkT + (size_t)((g * CG_ + c) * 9 + k) * C_ + ocb;
                float wv[16];
#pragma unroll
                for (int o = 0; o < 16; ++o) wv[o] = wp[o];
#pragma unroll
                for (int o = 0; o < 16; ++o)
                    acc[o] = fmaf(s, wv[o], acc[o]);
            }
        }
    }

#pragma unroll
    for (int o = 0; o < 16; ++o)
        out[((size_t)(b * C_ + ocb + o)) * HW_ + pix] = acc[o];
}

// ---------------------------------------------------------------------------
extern "C" void kernel_launch(void* const* d_in, const int* in_sizes, int n_in,
                              void* d_out, int out_size, void* d_ws, size_t ws_size,
                              hipStream_t stream)
{
    const float* x    = (const float*)d_in[0];
    const float* ef   = (const float*)d_in[1];
    const float* flow = (const float*)d_in[2];
    const float* w1   = (const float*)d_in[3];
    const float* b1   = (const float*)d_in[4];
    const float* w2   = (const float*)d_in[5];
    const float* b2   = (const float*)d_in[6];
    const float* w3   = (const float*)d_in[7];
    const float* b3   = (const float*)d_in[8];
    const float* wk   = (const float*)d_in[9];
    float* out = (float*)d_out;

    // Workspace layout (floats):
    //   h1:  B*64*HW   = 2,097,152
    //   h2:  B*64*HW   = 2,097,152
    //   om:  B*432*HW  = 14,155,776
    //   wt1: 1152*64   = 73,728
    //   wt2: 576*64    = 36,864
    //   wt3: 576*432   = 248,832
    //   wkT: 576*64    = 36,864          total ~75.1 MB
    float* h1  = (float*)d_ws;
    float* h2  = h1 + (size_t)B_ * C_ * HW_;
    float* om  = h2 + (size_t)B_ * C_ * HW_;
    float* wt1 = om + (size_t)B_ * OFFC_ * HW_;
    float* wt2 = wt1 + 1152 * 64;
    float* wt3 = wt2 + 576 * 64;
    float* wkT = wt3 + 576 * 432;

    transpose_w_k<64, 1152><<<dim3((64 * 1152 + 255) / 256), 256, 0, stream>>>(w1, wt1);
    transpose_w_k<64, 576><<<dim3((64 * 576 + 255) / 256), 256, 0, stream>>>(w2, wt2);
    transpose_w_k<432, 576><<<dim3((432 * 576 + 255) / 256), 256, 0, stream>>>(w3, wt3);
    transpose_w_k<64, 576><<<dim3((64 * 576 + 255) / 256), 256, 0, stream>>>(wk, wkT);

    dim3 blk(16, 16, 1);
    conv3x3_leaky_k<2 * C_, C_, 1><<<dim3(W_ / 16, H_ / 16, B_ * (C_ / 16)), blk, 0, stream>>>(ef, wt1, b1, h1);
    conv3x3_leaky_k<C_, C_, 1><<<dim3(W_ / 16, H_ / 16, B_ * (C_ / 16)), blk, 0, stream>>>(h1, wt2, b2, h2);
    conv3_off_k<2><<<dim3(W_ / 16, H_ / 32, B_ * (OFFC_ / 16)), blk, 0, stream>>>(h2, wt3, b3, flow, om);
    deform_k<<<dim3(W_ / 16, H_ / 16, B_ * (C_ / 16)), blk, 0, stream>>>(x, om, wkT, out);
}